// Round 5
// baseline (208.113 us; speedup 1.0000x reference)
//
#include <hip/hip_runtime.h>
#include <math.h>

// Problem constants (fixed by reference)
#define GRIDN   14
#define BOXN    2
#define LABELN  20
#define ALL_BOX 10          // 5*BOXN
#define CCH     30          // ALL_BOX + LABELN channels per cell

// R12: global_load_lds DMA pipeline, depth-3, quad-buffered LDS.
// R7-R11 post-mortems: four structurally distinct schedules (convoy, 4x
// occupancy, drain-free barrier, depth-2 counted-vmcnt register pipeline)
// all deliver 2.4-2.8 TB/s. In-flight bytes and flight windows were ample
// in R11 -> if concurrency rises and rate doesn't, it's a rate cap OR a
// residual coupling in the VGPR round-trip (ds_write waits / issue cost).
// This round removes the round-trip entirely with the guide's proven lever:
// __builtin_amdgcn_global_load_lds (HBM -> LDS DMA, vmcnt-counted, LDS dest
// = wave-uniform base + lane*16, per-lane global source). Per iteration the
// wave does exactly: counted s_waitcnt vmcnt(N) -> s_barrier -> issue next
// tile's DMAs -> compute. vmcnt never drains to 0 mid-loop; three tiles in
// flight per block at all times.
//  - TCELLS=64 -> 15,360 B/tile-buffer; NBUF=4 -> 61,440 B LDS, 2 blocks/CU.
//  - Each wave issues {4,4,4,3} DMAs per tile (chunk i active iff
//    i*256 + wave*64 < 960). Waiting for tile t with 2 tiles ahead in
//    flight = vmcnt(2*n_w): wave<3 -> 8, wave3 -> 6; tail: 4/3, then 0.
//  - WAR safety: STAGE(t+3 -> buf (k+3)&3) issued after barrier(k); that
//    buffer was read at iter k-1 and every wave's compute(k-1) precedes
//    barrier(k) in program order.
#define TCELLS  64          // cells per tile
#define TF4     480         // float4 per tensor per tile (64*30/4)
#define VTOT    960         // float4 per tile (preds+truths)
#define NBUF    4           // LDS buffers (depth-3 prefetch)
#define NCHUNK  4           // ceil(VTOT/256) DMA chunks per tile
#define PBLOCKS 512         // persistent blocks (2/CU, LDS-limited)

typedef float vfloat4 __attribute__((ext_vector_type(4)));

__global__ void yolo_zero_kernel(float* out, int n) {
    int i = blockIdx.x * blockDim.x + threadIdx.x;
    if (i < n) out[i] = 0.0f;
}

// Validated per-cell loss math (absmax 0 in rounds 1-11). Unchanged.
__device__ __forceinline__ float cell_loss(const float* p, const float* t) {
#pragma clang fp contract(off)
    const float CELL = (float)(1.0 / (double)GRIDN);

    const float tx = t[0], ty = t[1], tw = t[2], th_ = t[3], tconf = t[4];
    const bool obj = tconf > 0.0f;

    const float tcx = CELL * tx, tcy = CELL * ty;
    const float thx = tw * 0.5f, thy = th_ * 0.5f;
    const float tltx = tcx - thx, tlty = tcy - thy;
    const float trbx = tcx + thx, trby = tcy + thy;
    const float ta = (trbx - tltx) * (trby - tlty);

    float iou[BOXN], conf[BOXN];
#pragma unroll
    for (int b = 0; b < BOXN; ++b) {
        const float bx = p[b * 5 + 0], by = p[b * 5 + 1];
        const float bw = p[b * 5 + 2], bh = p[b * 5 + 3];
        conf[b] = p[b * 5 + 4];
        const float pcx = CELL * bx, pcy = CELL * by;
        const float phx = bw * 0.5f, phy = bh * 0.5f;
        const float pltx = pcx - phx, plty = pcy - phy;
        const float prbx = pcx + phx, prby = pcy + phy;
        const float ltx = fmaxf(pltx, tltx), lty = fmaxf(plty, tlty);
        const float rbx = fminf(prbx, trbx), rby = fminf(prby, trby);
        const float whx = fmaxf(rbx - ltx, 0.0f);
        const float why = fmaxf(rby - lty, 0.0f);
        const float inter = whx * why;
        const float pa = (prbx - pltx) * (prby - plty);
        iou[b] = inter / (pa + ta - inter);
    }

    const float max_iou = fmaxf(iou[0], iou[1]);
    bool r1;
    if (iou[0] == iou[1]) r1 = !(conf[0] >= conf[1]);
    else                  r1 = !(iou[0] > iou[1]);

    const float rx = r1 ? p[5] : p[0];
    const float ry = r1 ? p[6] : p[1];
    const float rw = r1 ? p[7] : p[2];
    const float rh = r1 ? p[8] : p[3];
    const float rc = r1 ? p[9] : p[4];

    const float dcx = rx - tx;
    const float dcy = ry - ty;
    const float center = dcx * dcx + dcy * dcy;

    const float dsx = sqrtf(rw) - sqrtf(tw);
    const float dsy = sqrtf(rh) - sqrtf(th_);
    const float size = dsx * dsx + dsy * dsy;

    const float dconf = rc - max_iou;
    const float conf_resp = dconf * dconf;

    const float c_other = r1 ? conf[0] : conf[1];
    const float conf_noresp = c_other * c_other;

    const float conf_noobj = conf[0] * conf[0] + conf[1] * conf[1];

    float label = 0.0f;
#pragma unroll
    for (int k = ALL_BOX; k < CCH; ++k) {
        const float d = p[k] - t[k];
        label += d * d;
    }

    const float w  = obj ? 1.0f : 0.0f;
    const float nw = obj ? 0.0f : 1.0f;
    return w * (5.0f * (center + size) + conf_resp + 0.5f * conf_noresp + label)
         + nw * (0.5f * conf_noobj);
}

#define WAITV(n) asm volatile("s_waitcnt vmcnt(" #n ")" ::: "memory")

__global__ __launch_bounds__(256, 2) void yolo_loss_kernel(
    const float* __restrict__ preds,
    const float* __restrict__ truths,
    float* __restrict__ out,
    int ntiles)
{
#pragma clang fp contract(off)
    __shared__ vfloat4 sbuf[NBUF * VTOT];   // 61,440 B -> 2 blocks/CU

    const int tid   = threadIdx.x;
    const int wave  = tid >> 6;
    const int wbase = tid & ~63;            // wave*64, wave-uniform

    const vfloat4* pp = (const vfloat4*)preds;
    const vfloat4* tp = (const vfloat4*)truths;

    // Issue this wave's DMA chunks for tile tt into LDS buffer b.
    // Chunk-wave activity (i*256 + wbase < VTOT) is wave-uniform; the
    // GLOBAL source address is per-lane (may straddle preds/truths); the
    // LDS destination is the wave-uniform chunk base (+lane*16 by HW).
#define STAGE(tt, b)                                                         \
    do {                                                                     \
        const int gb_ = (tt) * TF4;                                          \
        _Pragma("unroll")                                                    \
        for (int i_ = 0; i_ < NCHUNK; ++i_) {                                \
            const int cb_ = i_ * 256 + wbase;                                \
            if (cb_ < VTOT) {                                                \
                const int v_ = i_ * 256 + tid;                               \
                const vfloat4* src_ = (v_ < TF4) ? (pp + gb_ + v_)           \
                                                 : (tp + gb_ + (v_ - TF4));  \
                __builtin_amdgcn_global_load_lds(                            \
                    (const __attribute__((address_space(1))) void*)src_,     \
                    (__attribute__((address_space(3))) void*)                \
                        (sbuf + (b) * VTOT + cb_),                           \
                    16, 0, 0);                                               \
            }                                                                \
        }                                                                    \
    } while (0)

    int t = blockIdx.x;
    if (t < ntiles)               STAGE(t, 0);
    if (t + PBLOCKS < ntiles)     STAGE(t + PBLOCKS, 1);
    if (t + 2 * PBLOCKS < ntiles) STAGE(t + 2 * PBLOCKS, 2);

    float acc = 0.0f;
    int k = 0;
    for (; t < ntiles; t += PBLOCKS, ++k) {
        // Tiles still in flight ahead of t (each = {4,4,4,3} DMAs/wave).
        const int a = (t + PBLOCKS < ntiles) + (t + 2 * PBLOCKS < ntiles);

        // Counted wait: block until tile t's DMAs are done, leaving the
        // 'a' newer tiles' DMAs in flight. Never vmcnt(0) mid-loop.
        if (a == 2)      { if (wave < 3) WAITV(8); else WAITV(6); }
        else if (a == 1) { if (wave < 3) WAITV(4); else WAITV(3); }
        else             { WAITV(0); }
        __builtin_amdgcn_s_barrier();       // raw barrier: no vmcnt drain
        __builtin_amdgcn_sched_barrier(0);  // pin: no compile-time motion

        // Refill the buffer freed at iter k-1 (all waves passed its reads).
        const int t3 = t + 3 * PBLOCKS;
        if (t3 < ntiles) STAGE(t3, (k + 3) & 3);

        // Compute tile t from LDS (wave 0 only; compute is ~10% busy at
        // most in all prior rounds -- this is a bandwidth kernel).
        const float* sf = (const float*)(sbuf + (k & 3) * VTOT);
        if (tid < TCELLS)
            acc += cell_loss(sf + tid * CCH, sf + TF4 * 4 + tid * CCH);
    }

    // Only wave 0 holds nonzero acc: shuffle-reduce, one atomic per block.
    if (tid < 64) {
#pragma unroll
        for (int off = 32; off > 0; off >>= 1) acc += __shfl_down(acc, off, 64);
        if (tid == 0) atomicAdd(out, acc * (1.0f / 4096.0f));
    }
}

extern "C" void kernel_launch(void* const* d_in, const int* in_sizes, int n_in,
                              void* d_out, int out_size, void* d_ws, size_t ws_size,
                              hipStream_t stream) {
    const float* preds  = (const float*)d_in[0];
    const float* truths = (const float*)d_in[1];
    float* out = (float*)d_out;

    const int ncells = in_sizes[0] / CCH;      // 802816
    const int ntiles = ncells / TCELLS;        // 12544 (exact)

    yolo_zero_kernel<<<(out_size + 255) / 256, 256, 0, stream>>>(out, out_size);
    yolo_loss_kernel<<<PBLOCKS, 256, 0, stream>>>(preds, truths, out, ntiles);
}